// Round 9
// baseline (129.252 us; speedup 1.0000x reference)
//
#include <hip/hip_runtime.h>

#define UNITS 256
#define NB 501               // num buckets
#define NBA 502              // A-table entries per unit (A[501] needed: idx=500)
#define STEPF 0.05f
#define LBF -17.0f
#define UBF 8.0f
#define RESIDUEF -17.05f     // LB - STEP
#define LOG2E 1.4426950408889634f

#define UPB 32               // units per block
#define PADF 503             // LDS row stride in floats (odd -> bank stagger)
                             // FULL table: 32*503*4 = 64384 B -> 2 blocks/CU,
                             // NO hot-window, NO branch, NO cold path.
#define THREADS 1024         // 16 waves; 2 blocks/CU
#define ROWS_PB 1024         // grid = 8 unit-tiles * 64 row-tiles = 512 = 2/CU
#define CHUNKS 8             // 8 chunks of 128 rows
#define RD 5                 // fenced ring depth (8 slots) -- r6/r8 structure
                             // proven live; deeper = more bytes in flight/wave

// native vector type: works with __builtin_nontemporal_store (HIP float4 is a
// class type and is rejected)
typedef float floatx4 __attribute__((ext_vector_type(4)));

// ---------------------------------------------------------------------------
// Single fused kernel.  Per block: 32 units x 1024 rows, 1024 threads.
//
// Phase 1 (prologue, ~1-2 us): build the f32 interpolation table for this
// block's 32 units DIRECTLY in LDS.  A[u,j] = (STEP*excl_cumsum(relu(v))[j]
// + RESIDUE + b[u]) * LOG2E.  Interp identity: A[j+1]-A[j] = STEP*w[j]*L2E,
// so log2e*logit = A[idx] + frac*(A[idx+1]-A[idx]), frac = t*20 - idx.
// One wave per unit (2 rounds of 16 waves), within-lane prefix + wave scan.
// This replaces the separate build kernel + gtab workspace + staging loads.
//
// Phase 2: r8's sched_barrier-fenced register ring (depth 5 now), each chunk:
// issue load c+5 | fence | interp+sigmoid on chunk c | nt-store | fence.
// Every element is ONE ds_read2_b32 (both endpoints) + ~12 VALU + 2 TRANS --
// the round-0..8 window-branch (+6-8 VALU in the LDS-address critical path)
// is gone because the whole table fits.
// ---------------------------------------------------------------------------
__global__ __launch_bounds__(THREADS, 8) void iso_main_kernel(
    const float* __restrict__ x, const float* __restrict__ v,
    const float* __restrict__ b, float* __restrict__ out) {
  __shared__ float tab[UPB * PADF];  // 64384 B

  const int bu = blockIdx.x & 7;            // unit tile 0..7 (UPB=32)
  const int bb = blockIdx.x >> 3;           // batch tile 0..63
  const int u0 = bu * UPB;
  const int tid = threadIdx.x;
  const int lane = tid & 63;
  const int wv = tid >> 6;                  // wave 0..15

  // ---- phase 1: build A-table for 32 units in LDS (2 units per wave) ----
#pragma unroll
  for (int r = 0; r < 2; ++r) {
    const int ul = wv * 2 + r;              // 0..31
    const int u = u0 + ul;
    const float* __restrict__ vu = v + u * NB;
    float pref[8];
    float run = 0.0f;
#pragma unroll
    for (int k = 0; k < 8; ++k) {
      const int j = lane * 8 + k;
      const float wvv = (j < NB) ? fmaxf(vu[j], 0.0f) : 0.0f;
      pref[k] = run;  // exclusive within-lane prefix
      run += wvv;
    }
    float s = run;    // inclusive wave scan of per-lane sums
#pragma unroll
    for (int d = 1; d < 64; d <<= 1) {
      const float o = __shfl_up(s, d, 64);
      if (lane >= d) s += o;
    }
    const float base = s - run;  // exclusive lane base
    const float off = RESIDUEF + b[u];
    float* __restrict__ dst = tab + ul * PADF;
#pragma unroll
    for (int k = 0; k < 8; ++k) {
      const int j = lane * 8 + k;
      if (j < NBA) {
        dst[j] = (STEPF * (base + pref[k]) + off) * LOG2E;
      }
    }
  }

  // ---- addressing (identical geometry to r8: 128 B wave-load segments) ----
  const int rowoff = tid >> 3;              // 0..127 within chunk
  const int col4 = tid & 7;                 // float4 col within 32-unit span
  const floatx4* __restrict__ x4 = reinterpret_cast<const floatx4*>(x);
  floatx4* __restrict__ o4 = reinterpret_cast<floatx4*>(out);
  const int g0 = (bb * ROWS_PB + rowoff) * (UNITS / 4) + bu * (UPB / 4) + col4;
  const int gstep = 128 * (UNITS / 4);      // 128 rows per chunk
  const int qrow = col4 * 4;                // this thread's first unit row

  // ---- prologue loads for the ring, then the only barrier ----
  floatx4 xv[8];    // fully unrolled below -> compile-time slot indices
#pragma unroll
  for (int c = 0; c < RD; ++c) xv[c & 7] = x4[g0 + c * gstep];
  __builtin_amdgcn_sched_barrier(0);
  __syncthreads();

  // ---- phase 2: depth-5 fenced ring over 8 chunks, branch-free body ----
#pragma unroll
  for (int c = 0; c < CHUNKS; ++c) {
    if (c + RD < CHUNKS)
      xv[(c + RD) & 7] = x4[g0 + (c + RD) * gstep];
    __builtin_amdgcn_sched_barrier(0);      // load issued before compute

    const floatx4 cur = xv[c & 7];
    const float xs[4] = {cur.x, cur.y, cur.z, cur.w};
    float os[4];
#pragma unroll
    for (int k = 0; k < 4; ++k) {
      const float xc = fminf(fmaxf(xs[k], LBF + 1e-9f), UBF - 1e-9f);
      const float t = xc - LBF + STEPF;     // xc + 17.05, in (0.05, 25.05)
      const float ft = t * 20.0f;           // 1/STEP == 20 exactly
      int idx = (int)ft;                    // bucket, >=1 by construction
      idx = idx > NB - 1 ? NB - 1 : idx;    // defensive upper clamp only
      const float f = ft - (float)idx;      // frac in [0,1)
      // both interp endpoints: single ds_read2_b32 (adjacent dwords)
      const float* p = &tab[(qrow + k) * PADF + idx];
      const float a0 = p[0];
      const float a1 = p[1];
      const float l2 = fmaf(f, a1 - a0, a0);  // log2e * logit
      const float e = __builtin_amdgcn_exp2f(-l2);
      os[k] = __builtin_amdgcn_rcpf(1.0f + e);
    }
    // write-once output: nt store keeps the 64 MB stream out of L2/L3
    floatx4 ov;
    ov.x = os[0]; ov.y = os[1]; ov.z = os[2]; ov.w = os[3];
    __builtin_nontemporal_store(ov, &o4[g0 + c * gstep]);
    __builtin_amdgcn_sched_barrier(0);      // store stays in its chunk
  }
}

extern "C" void kernel_launch(void* const* d_in, const int* in_sizes, int n_in,
                              void* d_out, int out_size, void* d_ws,
                              size_t ws_size, hipStream_t stream) {
  const float* x = (const float*)d_in[0];   // (65536, 256)
  const float* v = (const float*)d_in[1];   // (256, 501)
  const float* b = (const float*)d_in[2];   // (256,)
  float* out = (float*)d_out;               // (65536, 256)
  // d_ws unused: table is built in-kernel, in LDS.

  const int rows = out_size / UNITS;                  // 65536
  const int grid = (UNITS / UPB) * (rows / ROWS_PB);  // 8 * 64 = 512
  iso_main_kernel<<<grid, THREADS, 0, stream>>>(x, v, b, out);
}

// Round 10
// 122.195 us; speedup vs baseline: 1.0578x; 1.0578x over previous
//
#include <hip/hip_runtime.h>

#define UNITS 256
#define NB 501               // num buckets
#define STEPF 0.05f
#define LBF -17.0f
#define UBF 8.0f
#define RESIDUEF -17.05f     // LB - STEP
#define LOG2E 1.4426950408889634f

#define WLO 208              // hot window idx [208,432) -> x in [-6.65, 4.55)
#define WSZ 224              // P(cold) ~ 2.7e-6 -> ~45 elements take global path
#define UPB 32               // units per block; LDS = 32*225*8 = 57600 B
#define PADF2 225            // LDS row stride in float2 (odd -> bank stagger)
#define THREADS 1024         // 16 waves/block; 2 co-resident/CU
#define ROWS_PB 512          // ROUND-10: grid = 8 * 128 = 1024 blocks = 4/CU
                             // QUEUED (2 resident). All CU-internal levers are
                             // exhausted (occupancy 25->57% with zero effect);
                             // the one untested axis is dispatch granularity:
                             // static 2/CU has no rebalancing slack, the 6.3
                             // TB/s fill runs 65536 self-balancing blocks.
#define CHUNKS 4             // 4 chunks of 128 rows
#define RD 3                 // fenced ring depth -- r6/r8-proven live

// native vector type: works with __builtin_nontemporal_store and as a 128-bit
// "v" inline-asm operand (HIP float4 is a class type; neither works)
typedef float floatx4 __attribute__((ext_vector_type(4)));

// ---------------------------------------------------------------------------
// Kernel 1: full fused table -> d_ws (1.03 MB, L2-resident).
//   w  = relu(v[u,j])
//   C  = STEP*excl_cumsum(w)[j] + RESIDUE + b[u] - j*STEP*w
//   store (C*log2e, w*log2e):  sigmoid = rcp(1 + exp2(-(C2 + t*w2))),
//   t = clamp(x)+17.05.  One wave per unit, 8 buckets/lane.
// ---------------------------------------------------------------------------
__global__ __launch_bounds__(256) void build_table_kernel(
    const float* __restrict__ v, const float* __restrict__ b,
    float2* __restrict__ gtab) {
  const int lane = threadIdx.x & 63;
  const int wave = threadIdx.x >> 6;
  const int u = blockIdx.x * 4 + wave;
  if (u >= UNITS) return;

  const float* vu = v + u * NB;
  float w[8], pref[8];
  float run = 0.0f;
#pragma unroll
  for (int k = 0; k < 8; ++k) {
    const int j = lane * 8 + k;
    const float wv = (j < NB) ? fmaxf(vu[j], 0.0f) : 0.0f;
    w[k] = wv;
    pref[k] = run;  // exclusive within-lane prefix
    run += wv;
  }
  float s = run;    // inclusive wave scan of per-lane sums
#pragma unroll
  for (int d = 1; d < 64; d <<= 1) {
    const float o = __shfl_up(s, d, 64);
    if (lane >= d) s += o;
  }
  const float base = s - run;  // exclusive lane base
  const float off = RESIDUEF + b[u];
#pragma unroll
  for (int k = 0; k < 8; ++k) {
    const int j = lane * 8 + k;
    if (j < NB) {
      const float C = STEPF * (base + pref[k]) + off - (float)j * STEPF * w[k];
      gtab[u * NB + j] = make_float2(C * LOG2E, w[k] * LOG2E);
    }
  }
}

// ---------------------------------------------------------------------------
// Kernel 2: stream x -> out.  Per block: 32 units x 512 rows, 1024 threads.
// Identical structure to r8 (best measured: iso < 42 us) except the grid is
// oversubscribed 4x per CU for dispatch-level self-balancing.
//  - float2 hot window, 57600 B LDS -> 2 blocks co-resident/CU.
//  - depth-3 sched_barrier-fenced register ring (verified live in r6/r8:
//    precise counted vmcnt waits, loads issued ~3 chunks ahead, never
//    blocked behind NT-store retirement).
//  - 128 B contiguous wave-load segments; NT stores for the write-once out.
// ---------------------------------------------------------------------------
__global__ __launch_bounds__(THREADS, 8) void iso_main_kernel(
    const float* __restrict__ x, const float2* __restrict__ gtab,
    float* __restrict__ out) {
  __shared__ float2 tab[UPB * PADF2];  // 57600 B

  const int bu = blockIdx.x & 7;            // unit tile 0..7 (UPB=32)
  const int bb = blockIdx.x >> 3;           // batch tile 0..127
  const int u0 = bu * UPB;
  const int tid = threadIdx.x;

  // ---- stage hot window: 32 threads per unit, 7 float2 each ----
  {
    const int ul = tid >> 5;                // unit 0..31
    const int jt = tid & 31;
    const float2* __restrict__ src = gtab + (u0 + ul) * NB + WLO;
    float2* __restrict__ dst = tab + ul * PADF2;
#pragma unroll
    for (int r = 0; r < 7; ++r) {           // 7*32 = 224 entries, 256 B runs
      const int j = jt + r * 32;
      dst[j] = src[j];
    }
  }

  // ---- addressing (r8 geometry: 128 B wave-load segments) ----
  const int rowoff = tid >> 3;              // 0..127 within chunk
  const int col4 = tid & 7;                 // float4 col within 32-unit span
  const floatx4* __restrict__ x4 = reinterpret_cast<const floatx4*>(x);
  floatx4* __restrict__ o4 = reinterpret_cast<floatx4*>(out);
  const int g0 = (bb * ROWS_PB + rowoff) * (UNITS / 4) + bu * (UPB / 4) + col4;
  const int gstep = 128 * (UNITS / 4);      // 128 rows per chunk
  const int qbase = (col4 * 4) * PADF2;     // LDS base for this thread's units

  // ---- prologue: issue ring loads, pin them live, then the only barrier ----
  floatx4 xv[4];    // fully unrolled below -> compile-time slot indices
#pragma unroll
  for (int c = 0; c < RD; ++c) xv[c] = x4[g0 + c * gstep];
#pragma unroll
  for (int c = 0; c < RD; ++c) asm volatile("" : "+v"(xv[c]));
  __syncthreads();

  // ---- depth-3 fenced ring over 4 chunks ----
#pragma unroll
  for (int c = 0; c < CHUNKS; ++c) {
    if (c + RD < CHUNKS)
      xv[(c + RD) & 3] = x4[g0 + (c + RD) * gstep];
    __builtin_amdgcn_sched_barrier(0);      // load issued before compute

    const floatx4 cur = xv[c & 3];
    const float xs[4] = {cur.x, cur.y, cur.z, cur.w};
    float os[4];
#pragma unroll
    for (int k = 0; k < 4; ++k) {
      const float xc = fminf(fmaxf(xs[k], LBF + 1e-9f), UBF - 1e-9f);
      const float t = xc - LBF + STEPF;     // xc + 17.05, in (0.05, 25.05)
      int idx = (int)(t * 20.0f);           // 1/STEP == 20 exactly
      const unsigned iw = (unsigned)(idx - WLO);
      float2 cw;
      if (iw < WSZ) {                       // hot: one aligned ds_read_b64
        cw = tab[qbase + k * PADF2 + (int)iw];
      } else {                              // ~45 elements total: L2 hit
        idx = idx < 0 ? 0 : (idx > NB - 1 ? NB - 1 : idx);
        cw = gtab[(u0 + col4 * 4 + k) * NB + idx];
      }
      const float l2 = fmaf(t, cw.y, cw.x); // log2e * logit
      const float e = __builtin_amdgcn_exp2f(-l2);
      os[k] = __builtin_amdgcn_rcpf(1.0f + e);
    }
    // write-once output: nt store keeps the 64 MB stream out of L2/L3
    floatx4 ov;
    ov.x = os[0]; ov.y = os[1]; ov.z = os[2]; ov.w = os[3];
    __builtin_nontemporal_store(ov, &o4[g0 + c * gstep]);
    __builtin_amdgcn_sched_barrier(0);      // store stays in its chunk
  }
}

extern "C" void kernel_launch(void* const* d_in, const int* in_sizes, int n_in,
                              void* d_out, int out_size, void* d_ws,
                              size_t ws_size, hipStream_t stream) {
  const float* x = (const float*)d_in[0];   // (65536, 256)
  const float* v = (const float*)d_in[1];   // (256, 501)
  const float* b = (const float*)d_in[2];   // (256,)
  float* out = (float*)d_out;               // (65536, 256)
  float2* gtab = (float2*)d_ws;             // 256*501*8 B = 1.03 MB

  build_table_kernel<<<64, 256, 0, stream>>>(v, b, gtab);

  const int rows = out_size / UNITS;                  // 65536
  const int grid = (UNITS / UPB) * (rows / ROWS_PB);  // 8 * 128 = 1024
  iso_main_kernel<<<grid, THREADS, 0, stream>>>(x, gtab, out);
}